// Round 1
// baseline (201.175 us; speedup 1.0000x reference)
//
#include <hip/hip_runtime.h>

// RF grid-sample DAS beamforming.
// Shapes: d_tx[4,512,256] d_rx[128,512,256] apod[128,512,256] rf[4,128,3072] t0[4]
// out[4,512,256] fp32.
//
// Strategy: block = (pixel tile of 4096) x (chunk of 8 elements).
//  - Loop e in chunk: stage rf[a][e][:] for all 4 angles into LDS (48 KB),
//    then each thread interp-gathers for its 8 pixels x 4 angles, accumulating
//    in registers. Partial sums combined across the 16 e-chunks via fp32
//    atomicAdd (out zeroed by hipMemsetAsync; graph-capture safe).
//  - Data range: d_tx,d_rx uniform in [0,1535) and t0=0 => delay in [0,3070],
//    i1 <= 3071 = S-1, so taps are always in-range; clamp is a no-op safety.

#define A_N 4
#define E_N 128
#define S_N 3072
#define NPIX_N (512 * 256)
#define TPB 512                    // threads per block (8 waves)
#define PXT 8                      // pixels per thread
#define TILE (TPB * PXT)           // 4096 pixels per block
#define TILES (NPIX_N / TILE)      // 32
#define ESPLIT 16                  // e-chunks
#define EPB (E_N / ESPLIT)         // 8 elements per block
#define STAGE_ITERS ((A_N * S_N / 4) / TPB)  // 3072 float4 / 512 thr = 6

__global__ __launch_bounds__(TPB, 2) void das_kernel(
    const float* __restrict__ d_tx, const float* __restrict__ d_rx,
    const float* __restrict__ apod, const float* __restrict__ rf,
    const float* __restrict__ t0,  float* __restrict__ out)
{
    __shared__ float lds_rf[A_N * S_N];   // 48 KB: 4 angle rows of current e
    const int tid = threadIdx.x;
    const int px0 = blockIdx.x * TILE + tid;   // + k*TPB for k in [0,PXT)
    const int e0  = blockIdx.y * EPB;

    // Precompute staging source offsets (element index into rf, minus e*S term).
    int sbase[STAGE_ITERS];
#pragma unroll
    for (int j = 0; j < STAGE_ITERS; ++j) {
        int idx = tid + j * TPB;          // float4 index into lds_rf
        int a   = idx / (S_N / 4);        // 0..3
        int s4  = idx - a * (S_N / 4);
        sbase[j] = a * (E_N * S_N) + s4 * 4;
    }

    float acc[A_N][PXT];
    float dta[A_N][PXT];
#pragma unroll
    for (int a = 0; a < A_N; ++a) {
        const float t0a = t0[a];
#pragma unroll
        for (int k = 0; k < PXT; ++k) {
            dta[a][k] = d_tx[a * NPIX_N + px0 + k * TPB] - t0a;
            acc[a][k] = 0.0f;
        }
    }

    for (int ei = 0; ei < EPB; ++ei) {
        const int e = e0 + ei;
        __syncthreads();   // previous iteration's gathers done before overwrite
#pragma unroll
        for (int j = 0; j < STAGE_ITERS; ++j) {
            float4 v = *(const float4*)(rf + sbase[j] + e * S_N);
            ((float4*)lds_rf)[tid + j * TPB] = v;
        }
        __syncthreads();

        const float* __restrict__ drx_row = d_rx + (size_t)e * NPIX_N;
        const float* __restrict__ ap_row  = apod + (size_t)e * NPIX_N;
#pragma unroll
        for (int k = 0; k < PXT; ++k) {
            const int p = px0 + k * TPB;
            const float drx = drx_row[p];
            const float ap  = ap_row[p];
#pragma unroll
            for (int a = 0; a < A_N; ++a) {
                float delay = dta[a][k] + drx;
                float x0 = floorf(delay);
                float w  = delay - x0;
                int i0 = (int)x0;
                i0 = min(max(i0, 0), S_N - 2);   // no-op for this data; safety
                float v0 = lds_rf[a * S_N + i0];
                float v1 = lds_rf[a * S_N + i0 + 1];
                acc[a][k] += (v0 + w * (v1 - v0)) * ap;
            }
        }
    }

#pragma unroll
    for (int a = 0; a < A_N; ++a)
#pragma unroll
        for (int k = 0; k < PXT; ++k)
            atomicAdd(&out[a * NPIX_N + px0 + k * TPB], acc[a][k]);
}

extern "C" void kernel_launch(void* const* d_in, const int* in_sizes, int n_in,
                              void* d_out, int out_size, void* d_ws, size_t ws_size,
                              hipStream_t stream) {
    const float* d_tx = (const float*)d_in[0];
    const float* d_rx = (const float*)d_in[1];
    const float* apod = (const float*)d_in[2];
    const float* rf   = (const float*)d_in[3];
    const float* t0   = (const float*)d_in[4];
    float* out = (float*)d_out;

    hipMemsetAsync(out, 0, (size_t)out_size * sizeof(float), stream);
    dim3 grid(TILES, ESPLIT);
    das_kernel<<<grid, TPB, 0, stream>>>(d_tx, d_rx, apod, rf, t0, out);
}